// Round 7
// baseline (201.158 us; speedup 1.0000x reference)
//
#include <hip/hip_runtime.h>

#define S_NODES 512          // nodes per bucket (dst_local = dst & 511)
#define S_SHIFT 9
#define CAP     10240        // bucket capacity (mean ~8163, 25% slack)
#define CHUNK   8192         // edges per scatter block
#define NREP    4            // LDS accumulator replicas in agg kernels

// Fold weights (redundantly per block) + per-node dots, grid-stride.
// Block 0 additionally zeroes cursor[] and publishes c01 = {c0, c1}.
// wv layout: [0:64)=w_a, [64:128)=w_b, [128:192)=w_c
__global__ __launch_bounds__(512) void fold_dots_kernel(
    const float* __restrict__ x,
    const float* __restrict__ Wl1, const float* __restrict__ Wr1, const float* __restrict__ b1,
    const float* __restrict__ Wl2, const float* __restrict__ Wr2, const float* __restrict__ b2,
    const float* __restrict__ Wfc1, const float* __restrict__ bfc1,
    const float* __restrict__ Wfc2, const float* __restrict__ bfc2,
    float* __restrict__ ga, float2* __restrict__ gbc, float* __restrict__ c01,
    int* __restrict__ cursor, int N)
{
    __shared__ float u[128], vl2[128], vr2[128], w2[32], wv[192];
    int t = threadIdx.x;
    if (blockIdx.x == 0 && t < 256) cursor[t] = 0;
    if (t < 32) w2[t] = Wfc2[t];
    __syncthreads();
    if (t < 128) {   // u = Wfc1 @ Wfc2   (Wfc1 [128,32] row-major)
        float s = 0.f;
        for (int k = 0; k < 32; ++k) s += Wfc1[t * 32 + k] * w2[k];
        u[t] = s;
    }
    __syncthreads();
    if (t < 128) {   // vl2 = Wl2 @ u, vr2 = Wr2 @ u   ([128,128] row-major)
        float a = 0.f, b = 0.f;
        for (int k = 0; k < 128; ++k) {
            a += Wl2[t * 128 + k] * u[k];
            b += Wr2[t * 128 + k] * u[k];
        }
        vl2[t] = a; vr2[t] = b;
    }
    __syncthreads();
    if (t < 64) {    // w_a, w_b, w_c   (Wl1/Wr1 [64,128] row-major)
        float wa = 0.f, wb = 0.f, wc = 0.f;
        for (int j = 0; j < 128; ++j) {
            float l1 = Wl1[t * 128 + j], r1 = Wr1[t * 128 + j];
            wc += l1 * vl2[j];
            wb += l1 * vr2[j] + r1 * vl2[j];
            wa += r1 * vr2[j];
        }
        wv[t] = wa; wv[64 + t] = wb; wv[128 + t] = wc;
    }
    if (blockIdx.x == 0 && t == 0) {
        float c0 = bfc2[0], c1 = 0.f;
        for (int j = 0; j < 128; ++j) {
            c0 += b1[j] * vr2[j] + b2[j] * u[j];
            c1 += b1[j] * vl2[j];
        }
        for (int k = 0; k < 32; ++k) c0 += bfc1[k] * w2[k];
        c01[0] = c0; c01[1] = c1;
    }
    __syncthreads();
    int lane = t & 63, sub = t >> 6;   // 8 nodes per block-iteration (one per wave)
    float wa = wv[lane], wb = wv[64 + lane], wc = wv[128 + lane];
    int ngroups = (N + 7) / 8;
    for (int g = blockIdx.x; g < ngroups; g += gridDim.x) {
        int node = g * 8 + sub;
        if (node >= N) continue;
        float v = x[(size_t)node * 64 + lane];
        float a = v * wa, b = v * wb, c = v * wc;
        for (int off = 32; off > 0; off >>= 1) {
            a += __shfl_down(a, off);
            b += __shfl_down(b, off);
            c += __shfl_down(c, off);
        }
        if (lane == 0) { ga[node] = a; gbc[node] = make_float2(b, c); }
    }
}

// Bucket edges by dst>>9 with block-local write combining. Slim LDS (~3KB):
// no edge staging — phase 3 re-reads src/dst (L2-hot) and recomputes the pack.
// Packed edge: (src << 9) | (dst & 511)  (src < 2^17 -> 26 bits).
__global__ __launch_bounds__(256) void scatter_kernel(
    const int* __restrict__ src, const int* __restrict__ dst, int E, int B,
    int* __restrict__ cursor, unsigned* __restrict__ bucket)
{
    __shared__ int hist[256], lbase[256], lcur[256];
    int t = threadIdx.x;
    int e0 = blockIdx.x * CHUNK;
    int cnt = E - e0; if (cnt > CHUNK) cnt = CHUNK;
    hist[t] = 0;
    __syncthreads();
    for (int i = t; i < cnt; i += 256)
        atomicAdd(&hist[dst[e0 + i] >> S_SHIFT], 1);
    __syncthreads();
    if (t < B && hist[t] > 0) lbase[t] = atomicAdd(&cursor[t], hist[t]);
    lcur[t] = 0;
    __syncthreads();
    for (int i = t; i < cnt; i += 256) {
        int d = dst[e0 + i], s = src[e0 + i];   // L2-hit re-read
        int b = d >> S_SHIFT;
        int off = atomicAdd(&lcur[b], 1);
        bucket[(size_t)b * CAP + (unsigned)(lbase[b] + off)] =
            ((unsigned)s << S_SHIFT) | (unsigned)(d & (S_NODES - 1));
    }
}

// One block per bucket, 1024 threads, 4-way replicated LDS accumulators.
__global__ __launch_bounds__(1024) void aggA_kernel(
    const unsigned* __restrict__ bucket, const int* __restrict__ cursor,
    const float2* __restrict__ gbc, const float* __restrict__ ga,
    const float* __restrict__ c01,
    float* __restrict__ q, float* __restrict__ t1, float* __restrict__ inv, int N)
{
    __shared__ float aB[NREP][S_NODES], aC[NREP][S_NODES];
    __shared__ int cnt[NREP][S_NODES];
    int t = threadIdx.x, b = blockIdx.x;
    int r = (t >> 6) & (NREP - 1);
    for (int i = t; i < NREP * S_NODES; i += 1024) {
        aB[0][i] = 0.f; aC[0][i] = 0.f; cnt[0][i] = 0;
    }
    __syncthreads();
    int n = cursor[b];
    const unsigned* bp = bucket + (size_t)b * CAP;
    for (int i = t; i < n; i += 1024) {
        unsigned uu = bp[i];
        float2 g = gbc[uu >> S_SHIFT];   // 8B gather, 800KB L2-resident table
        int dl = uu & (S_NODES - 1);
        atomicAdd(&aB[r][dl], g.x);
        atomicAdd(&aC[r][dl], g.y);
        atomicAdd(&cnt[r][dl], 1);
    }
    __syncthreads();
    if (t < S_NODES) {
        int node = (b << S_SHIFT) + t;
        if (node < N) {
            float sb = aB[0][t] + aB[1][t] + aB[2][t] + aB[3][t];
            float sc = aC[0][t] + aC[1][t] + aC[2][t] + aC[3][t];
            int d = cnt[0][t] + cnt[1][t] + cnt[2][t] + cnt[3][t];
            float iv = 1.0f / ((d > 0) ? (float)d : 1.0f);
            inv[node] = iv;
            q[node]   = iv * sc;
            t1[node]  = ga[node] + iv * sb + c01[0] + (d > 0 ? c01[1] : 0.f);
        }
    }
}

__global__ __launch_bounds__(1024) void aggB_kernel(
    const unsigned* __restrict__ bucket, const int* __restrict__ cursor,
    const float* __restrict__ q, const float* __restrict__ t1,
    const float* __restrict__ inv, float* __restrict__ out, int N)
{
    __shared__ float a2[NREP][S_NODES];
    int t = threadIdx.x, b = blockIdx.x;
    int r = (t >> 6) & (NREP - 1);
    for (int i = t; i < NREP * S_NODES; i += 1024) a2[0][i] = 0.f;
    __syncthreads();
    int n = cursor[b];
    const unsigned* bp = bucket + (size_t)b * CAP;
    for (int i = t; i < n; i += 1024) {
        unsigned uu = bp[i];
        atomicAdd(&a2[r][uu & (S_NODES - 1)], q[uu >> S_SHIFT]);
    }
    __syncthreads();
    if (t < S_NODES) {
        int node = (b << S_SHIFT) + t;
        if (node < N)
            out[node] = t1[node] + inv[node] * (a2[0][t] + a2[1][t] + a2[2][t] + a2[3][t]);
    }
}

extern "C" void kernel_launch(void* const* d_in, const int* in_sizes, int n_in,
                              void* d_out, int out_size, void* d_ws, size_t ws_size,
                              hipStream_t stream) {
    const float* x    = (const float*)d_in[0];
    const int*   eidx = (const int*)d_in[1];   // [2, E]
    // d_in[2] = edge_weight: unused by the reference
    const float* Wl1  = (const float*)d_in[3];
    const float* Wr1  = (const float*)d_in[4];
    const float* b1   = (const float*)d_in[5];
    const float* Wl2  = (const float*)d_in[6];
    const float* Wr2  = (const float*)d_in[7];
    const float* b2   = (const float*)d_in[8];
    const float* Wfc1 = (const float*)d_in[9];
    const float* bfc1 = (const float*)d_in[10];
    const float* Wfc2 = (const float*)d_in[11];
    const float* bfc2 = (const float*)d_in[12];

    const int N = in_sizes[0] / 64;
    const int E = in_sizes[2];
    const int* src = eidx;
    const int* dst = eidx + E;
    const int B = (N + S_NODES - 1) / S_NODES;       // 196 buckets (<= 256)
    const int nscat = (E + CHUNK - 1) / CHUNK;       // 196 scatter blocks

    // workspace: [cursor 1KB][c01 1KB][ga 4N][q 4N][t1 4N][inv 4N][gbc 8N][bucket B*CAP*4]
    char* ws = (char*)d_ws;
    int*      cursor = (int*)(ws);
    float*    c01    = (float*)(ws + 1024);
    float*    ga     = (float*)(ws + 2048);
    float*    q      = (float*)(ws + 2048 + (size_t)N * 4);
    float*    t1     = (float*)(ws + 2048 + (size_t)N * 8);
    float*    inv    = (float*)(ws + 2048 + (size_t)N * 12);
    float2*   gbc    = (float2*)(ws + 2048 + (size_t)N * 16);
    unsigned* bucket = (unsigned*)(ws + 2048 + (size_t)N * 24);

    fold_dots_kernel<<<256, 512, 0, stream>>>(
        x, Wl1, Wr1, b1, Wl2, Wr2, b2, Wfc1, bfc1, Wfc2, bfc2,
        ga, gbc, c01, cursor, N);

    scatter_kernel<<<nscat, 256, 0, stream>>>(src, dst, E, B, cursor, bucket);

    aggA_kernel<<<B, 1024, 0, stream>>>(bucket, cursor, gbc, ga, c01, q, t1, inv, N);
    aggB_kernel<<<B, 1024, 0, stream>>>(bucket, cursor, q, t1, inv, (float*)d_out, N);
}